// Round 2
// baseline (311.099 us; speedup 1.0000x reference)
//
#include <hip/hip_runtime.h>

// DAGMixer, wave-per-row persistent kernel.
// Per (b,t) row of H=2048:
//   logit = dot(orig_row, W_o) + dot(dag_row, W_d) + b
//   gate  = sigmoid(logit)
//   mixed = orig + gate * (dag - orig)
// Outputs concatenated: mixed (B*T*H floats) then gate (B*T floats).
//
// One 64-lane wave per row: lane l covers float4 indices l + k*64, k=0..7
// (coalesced 1KB per instruction). Reduction = 6 shfl_xor, no LDS, no
// __syncthreads -> waves on a CU desynchronize and keep the memory pipe fed.
// W fragments are lane-invariant across rows -> hoisted to registers once.

constexpr int H_DIM  = 2048;
constexpr int BLOCK  = 256;                  // 4 waves per block
constexpr int F4_ROW = H_DIM / 4;            // 512 float4 per row
constexpr int F4_PER = F4_ROW / 64;          // 8 float4 per lane per tensor

__global__ __launch_bounds__(BLOCK, 3) void dagmixer_wave(
    const float* __restrict__ orig,
    const float* __restrict__ dag,
    const float* __restrict__ Wg,      // [2*H] : W_o then W_d
    const float* __restrict__ bg,      // [1]
    float* __restrict__ mixed,         // [rows*H]
    float* __restrict__ gate_out,      // [rows]
    int rows)
{
    const int lane     = threadIdx.x & 63;
    const int wave_id  = (blockIdx.x * (BLOCK / 64)) + (threadIdx.x >> 6);
    const int n_waves  = gridDim.x * (BLOCK / 64);

    const float bias = bg[0];

    // Hoist W fragments: lane l always covers float4 columns l + k*64.
    const float4* wo4 = reinterpret_cast<const float4*>(Wg);
    const float4* wd4 = reinterpret_cast<const float4*>(Wg + H_DIM);
    float4 wo[F4_PER], wd[F4_PER];
#pragma unroll
    for (int k = 0; k < F4_PER; ++k) {
        wo[k] = wo4[lane + k * 64];
        wd[k] = wd4[lane + k * 64];
    }

    for (int row = wave_id; row < rows; row += n_waves) {
        const long long base4 = (long long)row * F4_ROW;
        const float4* o4 = reinterpret_cast<const float4*>(orig) + base4;
        const float4* d4 = reinterpret_cast<const float4*>(dag)  + base4;

        float4 o[F4_PER], d[F4_PER];
#pragma unroll
        for (int k = 0; k < F4_PER; ++k) {
            o[k] = o4[lane + k * 64];
            d[k] = d4[lane + k * 64];
        }

        float partial = 0.0f;
#pragma unroll
        for (int k = 0; k < F4_PER; ++k) {
            partial += o[k].x * wo[k].x + o[k].y * wo[k].y
                     + o[k].z * wo[k].z + o[k].w * wo[k].w;
            partial += d[k].x * wd[k].x + d[k].y * wd[k].y
                     + d[k].z * wd[k].z + d[k].w * wd[k].w;
        }

        // 64-lane butterfly: every lane ends with the full sum.
#pragma unroll
        for (int m = 32; m > 0; m >>= 1)
            partial += __shfl_xor(partial, m, 64);

        const float gate = 1.0f / (1.0f + __expf(-(partial + bias)));

        float4* m4 = reinterpret_cast<float4*>(mixed) + base4;
#pragma unroll
        for (int k = 0; k < F4_PER; ++k) {
            float4 m;
            m.x = fmaf(gate, d[k].x - o[k].x, o[k].x);
            m.y = fmaf(gate, d[k].y - o[k].y, o[k].y);
            m.z = fmaf(gate, d[k].z - o[k].z, o[k].z);
            m.w = fmaf(gate, d[k].w - o[k].w, o[k].w);
            m4[lane + k * 64] = m;
        }

        if (lane == 0) gate_out[row] = gate;
    }
}

extern "C" void kernel_launch(void* const* d_in, const int* in_sizes, int n_in,
                              void* d_out, int out_size, void* d_ws, size_t ws_size,
                              hipStream_t stream) {
    const float* orig = (const float*)d_in[0];
    const float* dag  = (const float*)d_in[1];
    const float* Wg   = (const float*)d_in[2];
    const float* bg   = (const float*)d_in[3];

    const int total = in_sizes[0];            // B*T*H
    const int rows  = total / H_DIM;          // B*T = 16384

    float* mixed    = (float*)d_out;
    float* gate_out = (float*)d_out + (long long)total;

    const int nblocks = 1024;                 // 4096 waves, 4 rows/wave
    dagmixer_wave<<<nblocks, BLOCK, 0, stream>>>(orig, dag, Wg, bg,
                                                 mixed, gate_out, rows);
}

// Round 4
// 296.566 us; speedup vs baseline: 1.0490x; 1.0490x over previous
//
#include <hip/hip_runtime.h>

// DAGMixer, wave-per-row persistent kernel with nontemporal (streaming)
// memory ops.
// Per (b,t) row of H=2048:
//   logit = dot(orig_row, W_o) + dot(dag_row, W_d) + b
//   gate  = sigmoid(logit)
//   mixed = orig + gate * (dag - orig)
// Outputs concatenated: mixed (B*T*H floats) then gate (B*T floats).
//
// Every byte of orig/dag is read exactly once and mixed is written exactly
// once and never re-read -> caching these streams is pure pollution. NT
// loads/stores set the `nt` bit so the store stream doesn't allocate in
// L2/L3 and evict the (harness-warmed) input lines.
//
// NOTE: __builtin_nontemporal_* requires a native clang vector type, not
// HIP's HIP_vector_type struct -> use ext_vector_type(4) throughout.

typedef float f4 __attribute__((ext_vector_type(4)));

constexpr int H_DIM  = 2048;
constexpr int BLOCK  = 256;                  // 4 waves per block
constexpr int F4_ROW = H_DIM / 4;            // 512 float4 per row
constexpr int F4_PER = F4_ROW / 64;          // 8 float4 per lane per tensor

__global__ __launch_bounds__(BLOCK) void dagmixer_nt(
    const float* __restrict__ orig,
    const float* __restrict__ dag,
    const float* __restrict__ Wg,      // [2*H] : W_o then W_d
    const float* __restrict__ bg,      // [1]
    float* __restrict__ mixed,         // [rows*H]
    float* __restrict__ gate_out,      // [rows]
    int rows)
{
    const int lane     = threadIdx.x & 63;
    const int wave_id  = (blockIdx.x * (BLOCK / 64)) + (threadIdx.x >> 6);
    const int n_waves  = gridDim.x * (BLOCK / 64);

    const float bias = bg[0];

    // W fragments are lane-invariant across rows: hoist into registers.
    const f4* wo4 = reinterpret_cast<const f4*>(Wg);
    const f4* wd4 = reinterpret_cast<const f4*>(Wg + H_DIM);
    f4 wo[F4_PER], wd[F4_PER];
#pragma unroll
    for (int k = 0; k < F4_PER; ++k) {
        wo[k] = wo4[lane + k * 64];
        wd[k] = wd4[lane + k * 64];
    }

    for (int row = wave_id; row < rows; row += n_waves) {
        const long long base4 = (long long)row * F4_ROW;
        const f4* o4 = reinterpret_cast<const f4*>(orig) + base4;
        const f4* d4 = reinterpret_cast<const f4*>(dag)  + base4;

        f4 o[F4_PER], d[F4_PER];
#pragma unroll
        for (int k = 0; k < F4_PER; ++k) {
            o[k] = __builtin_nontemporal_load(o4 + lane + k * 64);
            d[k] = __builtin_nontemporal_load(d4 + lane + k * 64);
        }

        float partial = 0.0f;
#pragma unroll
        for (int k = 0; k < F4_PER; ++k) {
            partial += o[k].x * wo[k].x + o[k].y * wo[k].y
                     + o[k].z * wo[k].z + o[k].w * wo[k].w;
            partial += d[k].x * wd[k].x + d[k].y * wd[k].y
                     + d[k].z * wd[k].z + d[k].w * wd[k].w;
        }

        // 64-lane butterfly: every lane ends with the full sum.
#pragma unroll
        for (int m = 32; m > 0; m >>= 1)
            partial += __shfl_xor(partial, m, 64);

        const float gate = 1.0f / (1.0f + __expf(-(partial + bias)));

        f4* m4 = reinterpret_cast<f4*>(mixed) + base4;
#pragma unroll
        for (int k = 0; k < F4_PER; ++k) {
            f4 m;
            m.x = fmaf(gate, d[k].x - o[k].x, o[k].x);
            m.y = fmaf(gate, d[k].y - o[k].y, o[k].y);
            m.z = fmaf(gate, d[k].z - o[k].z, o[k].z);
            m.w = fmaf(gate, d[k].w - o[k].w, o[k].w);
            __builtin_nontemporal_store(m, m4 + lane + k * 64);
        }

        if (lane == 0) gate_out[row] = gate;
    }
}

extern "C" void kernel_launch(void* const* d_in, const int* in_sizes, int n_in,
                              void* d_out, int out_size, void* d_ws, size_t ws_size,
                              hipStream_t stream) {
    const float* orig = (const float*)d_in[0];
    const float* dag  = (const float*)d_in[1];
    const float* Wg   = (const float*)d_in[2];
    const float* bg   = (const float*)d_in[3];

    const int total = in_sizes[0];            // B*T*H
    const int rows  = total / H_DIM;          // B*T = 16384

    float* mixed    = (float*)d_out;
    float* gate_out = (float*)d_out + (long long)total;

    const int nblocks = 2048;                 // 8192 waves, 2 rows/wave
    dagmixer_nt<<<nblocks, BLOCK, 0, stream>>>(orig, dag, Wg, bg,
                                               mixed, gate_out, rows);
}

// Round 5
// 295.433 us; speedup vs baseline: 1.0530x; 1.0038x over previous
//
#include <hip/hip_runtime.h>

// DAGMixer, wave-per-row, exact grid (1 row per wave), nontemporal streams.
// Per (b,t) row of H=2048:
//   logit = dot(orig_row, W_o) + dot(dag_row, W_d) + b
//   gate  = sigmoid(logit)
//   mixed = orig + gate * (dag - orig)
// Outputs concatenated: mixed (B*T*H floats) then gate (B*T floats).
//
// Every byte of orig/dag is read exactly once, mixed is written exactly once
// and never re-read -> NT loads/stores (`nt` bit) keep these streams from
// allocating in L2/L3 and evicting the harness-warmed input lines (R4: this
// took the kernel from 111us to <78us).
//
// NT builtins need native clang vectors, not HIP_vector_type -> ext_vector.

typedef float f4 __attribute__((ext_vector_type(4)));

constexpr int H_DIM  = 2048;
constexpr int BLOCK  = 256;                  // 4 waves per block
constexpr int F4_ROW = H_DIM / 4;            // 512 float4 per row
constexpr int F4_PER = F4_ROW / 64;          // 8 float4 per lane per tensor

__global__ __launch_bounds__(BLOCK) void dagmixer_nt1(
    const float* __restrict__ orig,
    const float* __restrict__ dag,
    const float* __restrict__ Wg,      // [2*H] : W_o then W_d
    const float* __restrict__ bg,      // [1]
    float* __restrict__ mixed,         // [rows*H]
    float* __restrict__ gate_out)      // [rows]
{
    const int lane = threadIdx.x & 63;
    const int row  = (blockIdx.x * (BLOCK / 64)) + (threadIdx.x >> 6);

    const float bias = bg[0];

    // W fragments are lane-invariant: lane l covers float4 cols l + k*64.
    const f4* wo4 = reinterpret_cast<const f4*>(Wg);
    const f4* wd4 = reinterpret_cast<const f4*>(Wg + H_DIM);

    const long long base4 = (long long)row * F4_ROW;
    const f4* o4 = reinterpret_cast<const f4*>(orig) + base4;
    const f4* d4 = reinterpret_cast<const f4*>(dag)  + base4;

    f4 o[F4_PER], d[F4_PER], wo[F4_PER], wd[F4_PER];
#pragma unroll
    for (int k = 0; k < F4_PER; ++k) {
        o[k]  = __builtin_nontemporal_load(o4 + lane + k * 64);
        d[k]  = __builtin_nontemporal_load(d4 + lane + k * 64);
        wo[k] = wo4[lane + k * 64];          // 16KB total, L2-resident
        wd[k] = wd4[lane + k * 64];
    }

    float partial = 0.0f;
#pragma unroll
    for (int k = 0; k < F4_PER; ++k) {
        partial += o[k].x * wo[k].x + o[k].y * wo[k].y
                 + o[k].z * wo[k].z + o[k].w * wo[k].w;
        partial += d[k].x * wd[k].x + d[k].y * wd[k].y
                 + d[k].z * wd[k].z + d[k].w * wd[k].w;
    }

    // 64-lane butterfly: every lane ends with the full sum.
#pragma unroll
    for (int m = 32; m > 0; m >>= 1)
        partial += __shfl_xor(partial, m, 64);

    const float gate = 1.0f / (1.0f + __expf(-(partial + bias)));

    f4* m4 = reinterpret_cast<f4*>(mixed) + base4;
#pragma unroll
    for (int k = 0; k < F4_PER; ++k) {
        f4 m;
        m.x = fmaf(gate, d[k].x - o[k].x, o[k].x);
        m.y = fmaf(gate, d[k].y - o[k].y, o[k].y);
        m.z = fmaf(gate, d[k].z - o[k].z, o[k].z);
        m.w = fmaf(gate, d[k].w - o[k].w, o[k].w);
        __builtin_nontemporal_store(m, m4 + lane + k * 64);
    }

    if (lane == 0) gate_out[row] = gate;
}

extern "C" void kernel_launch(void* const* d_in, const int* in_sizes, int n_in,
                              void* d_out, int out_size, void* d_ws, size_t ws_size,
                              hipStream_t stream) {
    const float* orig = (const float*)d_in[0];
    const float* dag  = (const float*)d_in[1];
    const float* Wg   = (const float*)d_in[2];
    const float* bg   = (const float*)d_in[3];

    const int total = in_sizes[0];            // B*T*H
    const int rows  = total / H_DIM;          // B*T = 16384

    float* mixed    = (float*)d_out;
    float* gate_out = (float*)d_out + (long long)total;

    const int nblocks = rows / (BLOCK / 64);  // 4096 blocks, 1 row per wave
    dagmixer_nt1<<<nblocks, BLOCK, 0, stream>>>(orig, dag, Wg, bg,
                                                mixed, gate_out);
}